// Round 6
// baseline (195.102 us; speedup 1.0000x reference)
//
#include <hip/hip_runtime.h>

// TaylorFeatureMap: x (2,16,2048,64) fp32 -> out (2,16,2048,2145) fp32
// Row layout per vector v:
//   [0]        = 1
//   [1..64]    = x[i] / 64^0.25
//   [65..128]  = x[i]^2 / (8*sqrt(2))
//   [129..2144]= x[i]*x[j] / 8, (i,j) = triu_indices(64, k=1) row-major
//
// R5: ZERO-BARRIER wave-private pipeline. One wave per block; the wave owns
// a private 34,320 B LDS buffer and grid-strides over 16 four-row groups.
// Correctness without any barrier: single wave => per-wave in-order DS
// execution orders gen g's ds_reads before gen g+1's ds_writes; compiler
// alias analysis preserves that order. Result: gen g+1's compute issues
// while gen g's global stores are in flight, and the 1024 wave-streams are
// never phase-locked (the R2/R4 bottleneck: barrier-synchronized blocks
// compute together then store together, idling the store pipe ~20%).
// Evidence the structure works: the harness fill kernel hits 6.6 TB/s at
// ~3.4 waves/CU with no barriers. 4 blocks/CU here (LDS-limited, 137 KB).
// Stores are dense aligned dwordx4 (group chunk = 2145 float4 exactly).

#define D 64
#define ROW 2145
#define OFFD_BASE 129
#define RPB 4                       // rows per group
#define CHUNK (RPB * ROW)           // 8580 floats = 34,320 B
#define NF4 (CHUNK / 4)             // 2145 float4 per group
#define NBLOCKS 1024

__global__ __launch_bounds__(64) void taylor_fm_kernel(
    const float* __restrict__ x, float* __restrict__ out, int ngroups) {
    __shared__ __align__(16) float buf[CHUNK];      // wave-private, 34,320 B
    const int lane = threadIdx.x;                   // 0..63

    const float inv_rrd   = 0.35355339059327373f;   // 1/64^0.25
    const float inv_rd_r2 = 0.08838834764831845f;   // 1/(8*sqrt(2))

    const float4* b4 = reinterpret_cast<const float4*>(buf);

    for (int grp = blockIdx.x; grp < ngroups; grp += NBLOCKS) {
        // ---- phase 1: compute 4 rows into private LDS ----
        const float* xg = x + (size_t)grp * (RPB * D);
#pragma unroll
        for (int r = 0; r < RPB; ++r) {
            const float xl = xg[r * D + lane];
            float* brow = buf + r * ROW;
            if (lane == 0) brow[0] = 1.0f;
            brow[1 + lane]  = xl * inv_rrd;
            brow[65 + lane] = xl * xl * inv_rd_r2;
            // exact pow2 pre-scale: (x_i/8)*x_j == (x_i*x_j)/8 bit-exactly
            const float xls = xl * 0.125f;
            float* tri = brow + OFFD_BASE;
#pragma unroll
            for (int i = 0; i < 63; ++i) {
                const int Ci = (i * (127 - i)) >> 1;   // segment start, row i
                float xi = __uint_as_float(
                    __builtin_amdgcn_readlane(__float_as_uint(xls), i));
                if (lane > i) {
                    tri[Ci - i - 1 + lane] = xi * xl;
                }
            }
        }

        // ---- phase 2: dense aligned float4 stream, batched 8-deep ----
        // (no barrier: single wave; DS ops retire in order)
        float4* o4 = reinterpret_cast<float4*>(out + (size_t)grp * CHUNK);
        int q = lane;
#pragma unroll
        for (int b = 0; b < 4; ++b) {               // 4 batches x 8 float4
            float4 r0 = b4[q],       r1 = b4[q + 64],  r2 = b4[q + 128],
                   r3 = b4[q + 192], r4 = b4[q + 256], r5 = b4[q + 320],
                   r6 = b4[q + 384], r7 = b4[q + 448];
            o4[q]       = r0; o4[q + 64]  = r1; o4[q + 128] = r2;
            o4[q + 192] = r3; o4[q + 256] = r4; o4[q + 320] = r5;
            o4[q + 384] = r6; o4[q + 448] = r7;
            q += 512;
        }
        // q = lane + 2048: one full round (2048+63 < 2145), then partial
        float4 ra = b4[q];
        o4[q] = ra;
        q += 64;
        if (q < NF4) {                              // lanes 0..32
            float4 rb = b4[q];
            o4[q] = rb;
        }
    }
}

extern "C" void kernel_launch(void* const* d_in, const int* in_sizes, int n_in,
                              void* d_out, int out_size, void* d_ws, size_t ws_size,
                              hipStream_t stream) {
    const float* x = (const float*)d_in[0];
    float* out = (float*)d_out;
    int nrows = in_sizes[0] / D;                    // 65536
    int ngroups = nrows / RPB;                      // 16384
    taylor_fm_kernel<<<NBLOCKS, 64, 0, stream>>>(x, out, ngroups);
}

// Round 7
// 116.441 us; speedup vs baseline: 1.6755x; 1.6755x over previous
//
#include <hip/hip_runtime.h>

// TaylorFeatureMap: x (2,16,2048,64) fp32 -> out (2,16,2048,2145) fp32
// Row layout per vector v:
//   [0]        = 1
//   [1..64]    = x[i] / 64^0.25
//   [65..128]  = x[i]^2 / (8*sqrt(2))
//   [129..2144]= x[i]*x[j] / 8, (i,j) = triu_indices(64, k=1) row-major
//
// R6 = R2 skeleton (compute rows into LDS, one __syncthreads, dense aligned
// dwordx4 store stream) with three refinements:
//  * 512 threads / 8 waves per block, RPB=4: waves {2r,2r+1} share row r,
//    splitting the triangle by i-parity (~1024 vs ~992 elems) -> phase-1
//    latency halved, 32 waves/CU (4 blocks x 8 waves; LDS 36.4 KB/block).
//  * masked triangle write replaced by cndmask ADDRESS select: inactive
//    lanes write to a per-wave scratch slot instead of using exec-mask
//    save/restore per i. Scratch is stride-1 (conflict-free); mixed
//    scratch/tri within a wave is <=2-way bank aliasing = free (m136).
//  * store phase uses all 8 waves (~4.2 float4/thread).
// R3/R5 lessons kept: no inline-asm barriers, no wave-private pipelines.

#define D 64
#define ROW 2145
#define OFFD_BASE 129
#define RPB 4                       // rows per block
#define NT 512                      // threads per block (8 waves)
#define CHUNK (RPB * ROW)           // 8580 floats = 34,320 B
#define NF4 (CHUNK / 4)             // 2145 float4 per block

__global__ __launch_bounds__(NT) void taylor_fm_kernel(
    const float* __restrict__ x, float* __restrict__ out) {
    __shared__ __align__(16) float buf[CHUNK];       // 34,320 B
    __shared__ float scratch[8][D];                  // 2,048 B dump slots

    const int wave = threadIdx.x >> 6;               // 0..7
    const int lane = threadIdx.x & 63;
    const int r    = wave >> 1;                      // row in group, 0..3
    const int half = wave & 1;                       // i-parity this wave owns

    const float xl = x[((size_t)blockIdx.x * RPB + r) * D + lane];

    float* brow = buf + r * ROW;
    float* dump = &scratch[wave][lane];

    if (half) {                                      // odd wave: head sections
        if (lane == 0) brow[0] = 1.0f;
        brow[1 + lane]  = xl * 0.35355339059327373f;     // x / 64^0.25
        brow[65 + lane] = xl * xl * 0.08838834764831845f; // x^2 / (8*sqrt2)
    }

    // exact pow2 pre-scale: (x_i/8)*x_j == (x_i*x_j)/8 bit-exactly
    const float xls = xl * 0.125f;
    float* tri = brow + OFFD_BASE;

    if (half == 0) {
#pragma unroll
        for (int i = 0; i < 63; i += 2) {            // even segments, 1024 el
            const int Ci = (i * (127 - i)) >> 1;
            float xi = __uint_as_float(
                __builtin_amdgcn_readlane(__float_as_uint(xls), i));
            float* p = (lane > i) ? &tri[Ci - i - 1 + lane] : dump;
            *p = xi * xl;
        }
    } else {
#pragma unroll
        for (int i = 1; i < 63; i += 2) {            // odd segments, 992 el
            const int Ci = (i * (127 - i)) >> 1;
            float xi = __uint_as_float(
                __builtin_amdgcn_readlane(__float_as_uint(xls), i));
            float* p = (lane > i) ? &tri[Ci - i - 1 + lane] : dump;
            *p = xi * xl;
        }
    }

    __syncthreads();

    // Dense aligned float4 stream: 2145 float4 per block, 8 waves.
    const float4* b4 = reinterpret_cast<const float4*>(buf);
    float4* o4 = reinterpret_cast<float4*>(out + (size_t)blockIdx.x * CHUNK);
    int q = threadIdx.x;
#pragma unroll
    for (int k = 0; k < 4; ++k, q += NT) {
        o4[q] = b4[q];
    }
    if (q < NF4) {                   // tail: 2145 - 4*512 = 97 float4
        o4[q] = b4[q];
    }
}

extern "C" void kernel_launch(void* const* d_in, const int* in_sizes, int n_in,
                              void* d_out, int out_size, void* d_ws, size_t ws_size,
                              hipStream_t stream) {
    const float* x = (const float*)d_in[0];
    float* out = (float*)d_out;
    int nrows = in_sizes[0] / D;                     // 65536
    taylor_fm_kernel<<<nrows / RPB, NT, 0, stream>>>(x, out);
}